// Round 16
// baseline (114.042 us; speedup 1.0000x reference)
//
#include <hip/hip_runtime.h>
#include <math.h>

#define NN 256
#define DD 128
#define HH 512

// ---------------- workspace layout (float offsets) ----------------
#define WS_XW    0         // fp16 [2][256][2048] panel Ae|Ce|Pp|(unused)   (524288 f)
#define WS_XEXT  524288    // [512][128] f32 (65536 f); dead after AB:
#define WS_EMB   524288    //   emb [2][256][128] (65536 f)
#define WS_INTRA 589824    //   intra [2][256][128] (65536 f)
#define WS_W4F   720896    // fp16 512 frags x 512 halves (131072 f); dead after AB:
#define WS_UPD   720896    //   upd [2][256][128] (65536 f)
#define WS_H1    1114112   // [512][512] f32 (262144 f)
#define WS_S     1376256   // [2][256][512] f32 (262144 f)
#define WS_WB5   1638400   // fp16 5 x 128 frags (163840 f)
#define WS_B4    1802240   // bias4 [2048] f32
#define WS_LGV   1804288   // lgv [2][256] f32
#define WS_QMT   1804800   // fp16 QmT [2][512][256] (131072 f)
// total 1935872 floats = 7.39 MB

typedef __attribute__((ext_vector_type(8))) _Float16 half8;
typedef __attribute__((ext_vector_type(4))) _Float16 half4v;
typedef __attribute__((ext_vector_type(4))) float f32x4;

__device__ __forceinline__ void gload_lds16(const _Float16* g, _Float16* l) {
  __builtin_amdgcn_global_load_lds(
      (const __attribute__((address_space(1))) unsigned*)g,
      (__attribute__((address_space(3))) unsigned*)l, 16, 0, 0);
}

#define WAITV(N) asm volatile("s_waitcnt vmcnt(" #N ")" ::: "memory")
#define RBARRIER() do { __builtin_amdgcn_s_barrier(); \
                        asm volatile("" ::: "memory"); } while (0)

// ================= prep kernel: all swizzles + Xext + bias4 =================
__global__ void prepk(const float* __restrict__ g1, const float* __restrict__ g2,
                      const float* __restrict__ eew1, const float* __restrict__ prw1,
                      const float* __restrict__ eeb1, const float* __restrict__ prb1,
                      const float* __restrict__ eeb2, const float* __restrict__ eew2,
                      const float* __restrict__ new1, const float* __restrict__ new2,
                      const float* __restrict__ prw2,
                      float* __restrict__ Xext, _Float16* __restrict__ W4f,
                      _Float16* __restrict__ Wb5, float* __restrict__ bias4)
{
  const int b = blockIdx.x, l = threadIdx.x;
  const int low = l & 15, q = l >> 4;
  if (b < 512) {                // big-4 weight frags (K=128, N=2048)
    const int f = b;
    const int kcI = f >> 7, ntI = f & 127;
    const int n = ntI * 16 + low, slice = n >> 9, np = n & 511;
    const int kb = kcI * 32 + q * 8;     // k in [0,128)
    half8 v;
    #pragma unroll
    for (int t = 0; t < 8; ++t) {
      const int k = kb + t;
      float val;
      if (slice == 0)      val = eew1[k * HH + np];
      else if (slice == 1) val = eew1[(384 + k) * HH + np];
      else if (slice == 2) val = prw1[k * HH + np];
      else                 val = prw1[(128 + k) * HH + np];
      v[t] = (_Float16)val;
    }
    *(half8*)&W4f[((size_t)f * 64 + l) * 8] = v;
  } else if (b < 1152) {        // five 128-frag weights
    const int idx = b - 512;
    const int which = idx >> 7, f = idx & 127;
    const float* src; int ld, nt;
    switch (which) {
      case 0:  src = eew2;            ld = 128; nt = 8;  break;   // W2f
      case 1:  src = prw1 + 256 * HH; ld = 512; nt = 32; break;   // WEf
      case 2:  src = new1;            ld = 512; nt = 32; break;   // W1nf
      case 3:  src = new2;            ld = 128; nt = 8;  break;   // W2nf
      default: src = prw2;            ld = 128; nt = 8;  break;   // PW2f
    }
    _Float16* dst = Wb5 + (size_t)which * 65536;
    const int kcI = f / nt, ntI = f % nt;
    const int n = ntI * 16 + low;
    const int kb = kcI * 32 + q * 8;
    half8 v;
    #pragma unroll
    for (int t = 0; t < 8; ++t) v[t] = (_Float16)src[(kb + t) * ld + n];
    *(half8*)&dst[((size_t)f * 64 + l) * 8] = v;
  } else if (b < 1664) {        // Xext rows = [g1; g2], 128 cols
    const int m = b - 1152;
    const int g = m >> 8, i = m & 255;
    const float* src = (g ? g2 : g1) + i * DD;
    float* dst = Xext + (size_t)m * DD;
    dst[l] = src[l];
    dst[64 + l] = src[64 + l];
  } else {                      // bias4
    const int n = (b - 1664) * 64 + l;
    float v = 0.f;
    if (n < 512) v = eeb1[n];
    else if (n >= 1024 && n < 1536) {
      const int h = n - 1024;
      float s = prb1[h];
      #pragma unroll 8
      for (int d = 0; d < 128; ++d) s = fmaf(eeb2[d], prw1[(256 + d) * HH + h], s);
      v = s;
    }
    bias4[n] = v;
  }
}

// ================= dual-config transposed MFMA GEMM =================
// oh: one-hot lookup add (f32 rows of eew1), z0 only.
// qmt: if set (z0), the n>=1536 slice (Qm) is written TRANSPOSED to
// qmt[g][h][j] instead of the panel — heavy reads it with consecutive-j
// half4v loads (R15 lesson: the scalar column-stride Qm loads were stage2's
// latency stall candidate).
template<int FT, int MT>
__global__ __launch_bounds__(256, 2)
void gemm2(const float* B0, const float* B1, int ldb0, int ldb1,
           float sc0, float sc1,
           const _Float16* A0, const _Float16* A1, int nt0, int nt1,
           int kcn0, int kcn1, const float* bias0, const float* bias1,
           const float* oh0, const float* oh1, _Float16* qmt,
           void* O0, void* O1, int ldo0, int ldo1,
           int half0, int half1, int relu0, int relu1, int ylim1)
{
  const int z = blockIdx.z;
  if (z == 1 && (int)blockIdx.y >= ylim1) return;
  const float* Bsrc = z ? B1 : B0;
  const _Float16* Af = z ? A1 : A0;
  const float* bias = z ? bias1 : bias0;
  const float* ohp = z ? oh1 : oh0;
  _Float16* qmtp = z ? nullptr : qmt;
  void* Out = z ? O1 : O0;
  const int ldb = z ? ldb1 : ldb0, ntTot = z ? nt1 : nt0;
  const int kcN = z ? kcn1 : kcn0, ldo = z ? ldo1 : ldo0;
  const int ohalf = z ? half1 : half0, orelu = z ? relu1 : relu0;
  const float sc = z ? sc1 : sc0;

  const int tid = threadIdx.x;
  const int w = tid >> 6, l = tid & 63, low = l & 15, q = l >> 4;
  const int mb = blockIdx.x * (MT * 16);
  const int nb = (blockIdx.y * 4 + w) * (FT * 16);
  f32x4 acc[FT][MT];
  #pragma unroll
  for (int ft = 0; ft < FT; ++ft)
    #pragma unroll
    for (int et = 0; et < MT; ++et) acc[ft][et] = (f32x4){0.f, 0.f, 0.f, 0.f};

  for (int kc = 0; kc < kcN; ++kc) {
    const int k0 = kc * 32 + q * 8;
    half8 bfr[MT];
    #pragma unroll
    for (int et = 0; et < MT; ++et) {
      const float* p = Bsrc + (size_t)(mb + et * 16 + low) * ldb + k0;
      const float4 b0 = *(const float4*)p;
      const float4 b1 = *(const float4*)(p + 4);
      half8 v;
      v[0] = (_Float16)(b0.x * sc); v[1] = (_Float16)(b0.y * sc);
      v[2] = (_Float16)(b0.z * sc); v[3] = (_Float16)(b0.w * sc);
      v[4] = (_Float16)(b1.x * sc); v[5] = (_Float16)(b1.y * sc);
      v[6] = (_Float16)(b1.z * sc); v[7] = (_Float16)(b1.w * sc);
      bfr[et] = v;
    }
    #pragma unroll
    for (int ft = 0; ft < FT; ++ft) {
      const int ng = (nb >> 4) + ft;
      const half8 af = *(const half8*)&Af[((size_t)(kc * ntTot + ng) * 64 + l) * 8];
      #pragma unroll
      for (int et = 0; et < MT; ++et)
        acc[ft][et] = __builtin_amdgcn_mfma_f32_16x16x32_f16(af, bfr[et], acc[ft][et], 0, 0, 0);
    }
  }
  #pragma unroll
  for (int ft = 0; ft < FT; ++ft) {
    const int n0 = nb + ft * 16 + q * 4;
    const float4 bs = *(const float4*)&bias[n0];
    #pragma unroll
    for (int et = 0; et < MT; ++et) {
      const int m = mb + et * 16 + low;
      float vx = acc[ft][et][0] + bs.x;
      float vy = acc[ft][et][1] + bs.y;
      float vz = acc[ft][et][2] + bs.z;
      float vw = acc[ft][et][3] + bs.w;
      if (ohp) {
        const int i = m & 255;
        if (n0 < 512) {
          const float4 ov = *(const float4*)&ohp[(size_t)(128 + i) * 512 + n0];
          vx += ov.x; vy += ov.y; vz += ov.z; vw += ov.w;
        } else if (n0 < 1024) {
          const float4 ov = *(const float4*)&ohp[(size_t)(512 + i) * 512 + (n0 - 512)];
          vx += ov.x; vy += ov.y; vz += ov.z; vw += ov.w;
        }
      }
      if (orelu) {
        vx = fmaxf(vx, 0.f); vy = fmaxf(vy, 0.f);
        vz = fmaxf(vz, 0.f); vw = fmaxf(vw, 0.f);
      }
      if (qmtp && n0 >= 1536) {
        // transposed store: qmt[g][h][j], h = n0-1536+r, j = m&255
        const int gI = m >> 8, jI = m & 255;
        _Float16* qp = qmtp + ((size_t)gI * 512 + (n0 - 1536)) * 256 + jI;
        qp[0]       = (_Float16)vx;
        qp[256]     = (_Float16)vy;
        qp[512]     = (_Float16)vz;
        qp[768]     = (_Float16)vw;
      } else if (ohalf) {
        half4v pk;
        pk[0] = (_Float16)vx; pk[1] = (_Float16)vy;
        pk[2] = (_Float16)vz; pk[3] = (_Float16)vw;
        *(half4v*)((_Float16*)Out + (size_t)m * ldo + n0) = pk;
      } else {
        *(float4*)((float*)Out + (size_t)m * ldo + n0) = make_float4(vx, vy, vz, vw);
      }
    }
  }
}

// ================= fused heavy edge kernel =================
// R13 structure (proven 68us) + QmT consecutive-j loads (this round's change):
// stage2's per-cc Qm access was 8 scalar 2B column-stride global loads; now
// 2 half4v loads hoisted right after the barrier so MFMA covers their latency.
__global__ __launch_bounds__(512, 4)
void heavy_mfma(const _Float16* __restrict__ XW, const _Float16* __restrict__ W2fg,
                const _Float16* __restrict__ WEf, const _Float16* __restrict__ QmT,
                float* __restrict__ SG)
{
  __shared__ _Float16 Ut[128 * DD];      // 32 KB, XOR-swizzled 8B blocks
  __shared__ _Float16 Sb[3][4096];       // 24 KB staging ring (W2f/WEf)
  __shared__ _Float16 AeH[HH];           // 1 KB
  __shared__ float PpL[HH];              // 2 KB
  __shared__ float Sp[8][HH];            // 16 KB per-wave S partials
  const int g = blockIdx.z, i = blockIdx.x;
  const int tid = threadIdx.x;
  const _Float16* Xg = XW + (size_t)g * NN * 2048;
  const _Float16* rowI = Xg + (size_t)i * 2048;
  const _Float16* Qt = QmT + (size_t)g * 512 * 256;
  const int w = tid >> 6, l = tid & 63, low = l & 15, q = l >> 4;
  const int xsw = (low & 7) << 1;
  const half8 hz = (half8)((_Float16)0);

  AeH[tid] = rowI[tid];
  PpL[tid] = (float)rowI[1024 + tid];
  #pragma unroll
  for (int t = 0; t < 8; ++t) ((float*)Sp)[tid + t * 512] = 0.f;

  for (int h2 = 0; h2 < 2; ++h2) {
    const int jb = h2 * 128;
    const int j = jb + w * 16 + low;     // this lane's j-row (16 per wave)
    const int e = w * 16 + low;          // local Ut row

    // ---------- stage 1: Ut[e][c] for this wave's 16 e ----------
    __syncthreads();                     // Sb WAR across halves/stages
    gload_lds16(W2fg + (size_t)w * 512 + l * 8, &Sb[0][w * 512]);
    gload_lds16(W2fg + 4096 + (size_t)w * 512 + l * 8, &Sb[1][w * 512]);
    {
      half8 ce_cur = *(const half8*)&Xg[(size_t)j * 2048 + 512 + q * 8];
      f32x4 acc[8];
      #pragma unroll
      for (int ct = 0; ct < 8; ++ct) acc[ct] = (f32x4){0.f, 0.f, 0.f, 0.f};
      for (int kc = 0; kc < 16; ++kc) {
        half8 ce_nxt = hz;
        if (kc < 15)
          ce_nxt = *(const half8*)&Xg[(size_t)j * 2048 + 512 + (kc + 1) * 32 + q * 8];
        if (kc == 0)       WAITV(1);
        else if (kc == 15) WAITV(0);
        else               WAITV(2);
        RBARRIER();
        if (kc < 14)
          gload_lds16(W2fg + (size_t)(kc + 2) * 4096 + w * 512 + l * 8,
                      &Sb[(kc + 2) % 3][w * 512]);
        const half8 a = *(const half8*)&AeH[kc * 32 + q * 8];
        const half8 bfr = __builtin_elementwise_max(a + ce_cur, hz);
        const _Float16* sb = &Sb[kc % 3][0];
        __builtin_amdgcn_s_setprio(1);
        #pragma unroll
        for (int ct = 0; ct < 8; ++ct) {
          const half8 wf = *(const half8*)&sb[ct * 512 + l * 8];
          acc[ct] = __builtin_amdgcn_mfma_f32_16x16x32_f16(wf, bfr, acc[ct], 0, 0, 0);
        }
        __builtin_amdgcn_s_setprio(0);
        ce_cur = ce_nxt;
      }
      // write Ut (wave-private rows)
      #pragma unroll
      for (int ct = 0; ct < 8; ++ct) {
        const int cb2 = ct * 4 + q;
        half4v pk;
        pk[0] = (_Float16)acc[ct][0]; pk[1] = (_Float16)acc[ct][1];
        pk[2] = (_Float16)acc[ct][2]; pk[3] = (_Float16)acc[ct][3];
        *(half4v*)&Ut[e * DD + ((cb2 ^ xsw) << 2)] = pk;
      }
    }

    // ---------- stage 2: WEf via ring; D2[m=e][n=h]; e-reduce via MFMA ----------
    __syncthreads();                     // Sb WAR: stage1 compute(15) read S0
    gload_lds16(WEf + (size_t)((w >> 1) * 32 + 0 + (w & 1)) * 512 + l * 8,
                &Sb[0][w * 512]);
    gload_lds16(WEf + (size_t)((w >> 1) * 32 + 2 + (w & 1)) * 512 + l * 8,
                &Sb[1][w * 512]);
    {
      half8 bfr2[4];
      #pragma unroll
      for (int kc2 = 0; kc2 < 4; ++kc2) {
        const int cb0 = kc2 * 8 + q * 2;
        bfr2[kc2] = *(const half8*)&Ut[e * DD + ((cb0 ^ xsw) << 2)];
      }
      const half4v onesv = {(_Float16)1.f, (_Float16)1.f, (_Float16)1.f, (_Float16)1.f};
      for (int cc = 0; cc < 16; ++cc) {
        if (cc == 15) WAITV(0);
        else          WAITV(1);
        RBARRIER();
        // hoisted QmT loads for this cc (consecutive-j half4v; latency
        // covered by the MFMA phase below)
        const _Float16* qr = &Qt[(size_t)(cc * 32 + low) * 256 + jb + w * 16 + q * 4];
        const half4v qv_0 = *(const half4v*)qr;
        const half4v qv_1 = *(const half4v*)(qr + 16 * 256);
        const _Float16* sb = &Sb[cc % 3][0];
        #pragma unroll
        for (int t = 0; t < 2; ++t) {
          const int hc = cc * 2 + t;
          const int h0 = hc * 16;
          f32x4 acc2 = (f32x4){0.f, 0.f, 0.f, 0.f};
          __builtin_amdgcn_s_setprio(1);
          #pragma unroll
          for (int kc2 = 0; kc2 < 4; ++kc2) {
            const half8 af = *(const half8*)&sb[(kc2 * 2 + t) * 512 + l * 8];
            acc2 = __builtin_amdgcn_mfma_f32_16x16x32_f16(bfr2[kc2], af, acc2, 0, 0, 0);
          }
          __builtin_amdgcn_s_setprio(0);
          const float pp = PpL[h0 + low];
          const half4v qv = t ? qv_1 : qv_0;
          half4v rv;
          #pragma unroll
          for (int r = 0; r < 4; ++r)
            rv[r] = (_Float16)fmaxf(pp + (float)qv[r] + acc2[r], 0.f);
          f32x4 red = __builtin_amdgcn_mfma_f32_16x16x16f16(
              rv, onesv, (f32x4){0.f, 0.f, 0.f, 0.f}, 0, 0, 0);
          if (low == 0) {
            float4* sp = (float4*)&Sp[w][h0 + q * 4];
            float4 v = *sp;
            v.x += red[0]; v.y += red[1]; v.z += red[2]; v.w += red[3];
            *sp = v;
          }
        }
        if (cc < 14)
          gload_lds16(WEf + (size_t)((w >> 1) * 32 + 2 * (cc + 2) + (w & 1)) * 512 + l * 8,
                      &Sb[(cc + 2) % 3][w * 512]);
      }
    }
  }
  __syncthreads();
  float s = 0.f;
  #pragma unroll
  for (int w2 = 0; w2 < 8; ++w2) s += Sp[w2][tid];
  SG[((size_t)g * NN + i) * HH + tid] = s;
}

// ====== fused interact + l2norm + update + logit row-dot; 512 threads ======
__global__ void interupd(const float* __restrict__ embG, const float* __restrict__ intraG,
                         const float* __restrict__ upw, const float* __restrict__ upb,
                         const float* __restrict__ agw,
                         float* __restrict__ updG, float* __restrict__ lgv)
{
  const int i = blockIdx.x, dir = blockIdx.y;
  const int tid = threadIdx.x, d = tid & 127, jc = tid >> 7;
  __shared__ float pN[4][DD], pS[4][DD], pdot[4][DD];
  __shared__ float vsm[3 * DD];
  __shared__ float pw[2][4];
  __shared__ float pw2[2];
  const float* A = embG + dir * NN * DD;
  const float* Bp = embG + (1 - dir) * NN * DD;
  const float av = A[i * DD + d];
  {
    float accN = 0.f, accS = 0.f;
    #pragma unroll 4
    for (int j = jc * 64; j < jc * 64 + 64; ++j) {
      const float bv = Bp[j * DD + d];
      accN = fmaf(bv, __expf(av * bv), accN);
      accS += bv;
    }
    pN[jc][d] = accN; pS[jc][d] = accS;
  }
  __syncthreads();
  float cv = 0.f, iv = 0.f;
  if (jc == 0) {
    const float accN = pN[0][d] + pN[1][d] + pN[2][d] + pN[3][d];
    const float accS = pS[0][d] + pS[1][d] + pS[2][d] + pS[3][d];
    cv = accN / (256.f * av * accS);
    iv = intraG[dir * NN * DD + i * DD + d];
    float q0 = av * av, q1 = iv * iv, q2 = cv * cv;
    #pragma unroll
    for (int st = 1; st < 64; st <<= 1) {
      q0 += __shfl_xor(q0, st);
      q1 += __shfl_xor(q1, st);
      q2 += __shfl_xor(q2, st);
    }
    const int w = d >> 6;
    if ((d & 63) == 0) { pw[w][0] = q0; pw[w][1] = q1; pw[w][2] = q2; }
  }
  __syncthreads();
  if (jc == 0) {
    const float n0 = 1.f / fmaxf(sqrtf(pw[0][0] + pw[1][0]), 1e-12f);
    const float n1 = 1.f / fmaxf(sqrtf(pw[0][1] + pw[1][1]), 1e-12f);
    const float n2 = 1.f / fmaxf(sqrtf(pw[0][2] + pw[1][2]), 1e-12f);
    vsm[d] = av * n0; vsm[DD + d] = iv * n1; vsm[2 * DD + d] = cv * n2;
  }
  __syncthreads();
  {
    float pd = (jc == 0) ? upb[d] : 0.f;
    #pragma unroll 8
    for (int k = jc * 96; k < jc * 96 + 96; ++k)
      pd = fmaf(vsm[k], upw[k * DD + d], pd);
    pdot[jc][d] = pd;
  }
  __syncthreads();
  if (jc == 0) {
    const float acc = pdot[0][d] + pdot[1][d] + pdot[2][d] + pdot[3][d];
    updG[dir * NN * DD + i * DD + d] = acc;
    float lp = acc * agw[d];
    #pragma unroll
    for (int st = 1; st < 64; st <<= 1) lp += __shfl_xor(lp, st);
    if ((d & 63) == 0) pw2[d >> 6] = lp;
  }
  __syncthreads();
  if (tid == 0) lgv[dir * NN + i] = pw2[0] + pw2[1];
}

// ==== aggregate: softmax(lgv) + weighted sum + cosine; 1024 threads ====
__global__ void aggfin(const float* __restrict__ updG, const float* __restrict__ lgv,
                       float* __restrict__ out)
{
  __shared__ float mp[2][4][DD];
  __shared__ float sg[2][NN];
  __shared__ float redd[1024];
  const int t = threadIdx.x;
  const int g = t >> 9, tl = t & 511, jc = tl >> 7, d = tl & 127;
  const float* U = updG + g * NN * DD;
  const float lg = (tl < NN) ? lgv[g * NN + tl] : -1e30f;
  redd[t] = lg;
  __syncthreads();
  for (int st = 256; st > 0; st >>= 1) {
    if (tl < st) redd[t] = fmaxf(redd[t], redd[t + st]);
    __syncthreads();
  }
  const float mx = redd[g << 9];
  __syncthreads();
  const float e = (tl < NN) ? __expf(lg - mx) : 0.f;
  redd[t] = e;
  __syncthreads();
  for (int st = 256; st > 0; st >>= 1) {
    if (tl < st) redd[t] += redd[t + st];
    __syncthreads();
  }
  if (tl < NN) sg[g][tl] = e / redd[g << 9];
  __syncthreads();
  {
    float rp = 0.f;
    #pragma unroll 4
    for (int jj = jc * 64; jj < jc * 64 + 64; ++jj)
      rp = fmaf(sg[g][jj], U[jj * DD + d], rp);
    mp[g][jc][d] = rp;
  }
  __syncthreads();
  if (t < DD) {
    const float r0 = mp[0][0][t] + mp[0][1][t] + mp[0][2][t] + mp[0][3][t];
    const float r1 = mp[1][0][t] + mp[1][1][t] + mp[1][2][t] + mp[1][3][t];
    redd[t] = r0 * r1; redd[128 + t] = r0 * r0; redd[256 + t] = r1 * r1;
  }
  __syncthreads();
  for (int st = 64; st > 0; st >>= 1) {
    if (t < st) redd[t] += redd[t + st];
    else if (t >= 128 && t < 128 + st) redd[t] += redd[t + st];
    else if (t >= 256 && t < 256 + st) redd[t] += redd[t + st];
    __syncthreads();
  }
  if (t == 0)
    out[0] = (redd[0] / fmaxf(sqrtf(redd[128]) * sqrtf(redd[256]), 1e-8f) + 1.f) * 0.5f;
}

extern "C" void kernel_launch(void* const* d_in, const int* in_sizes, int n_in,
                              void* d_out, int out_size, void* d_ws, size_t ws_size,
                              hipStream_t stream)
{
  (void)in_sizes; (void)n_in; (void)out_size; (void)ws_size;
  const float* g1   = (const float*)d_in[0];
  const float* g2   = (const float*)d_in[1];
  const float* new1 = (const float*)d_in[2];
  const float* neb1 = (const float*)d_in[3];
  const float* new2 = (const float*)d_in[4];
  const float* neb2 = (const float*)d_in[5];
  const float* eew1 = (const float*)d_in[6];
  const float* eeb1 = (const float*)d_in[7];
  const float* eew2 = (const float*)d_in[8];
  const float* eeb2 = (const float*)d_in[9];
  const float* prw1 = (const float*)d_in[10];
  const float* prb1 = (const float*)d_in[11];
  const float* prw2 = (const float*)d_in[12];
  const float* prb2 = (const float*)d_in[13];
  const float* upw  = (const float*)d_in[14];
  const float* upb  = (const float*)d_in[15];
  const float* agw  = (const float*)d_in[16];
  const float* agb  = (const float*)d_in[17];
  (void)agb; // constant logit shift cancels in softmax
  float* W = (float*)d_ws;
  float* out = (float*)d_out;

  _Float16* XW16 = (_Float16*)(W + WS_XW);
  float* Xext    = W + WS_XEXT;
  float* emb     = W + WS_EMB;
  float* intra   = W + WS_INTRA;
  _Float16* W4f  = (_Float16*)(W + WS_W4F);
  float* updv    = W + WS_UPD;
  float* H1      = W + WS_H1;
  float* Sv      = W + WS_S;
  _Float16* Wb5  = (_Float16*)(W + WS_WB5);
  float* bias4   = W + WS_B4;
  float* lgv     = W + WS_LGV;
  _Float16* QmT  = (_Float16*)(W + WS_QMT);
  _Float16* W2f  = Wb5;
  _Float16* WEf  = Wb5 + 65536;
  _Float16* W1nf = Wb5 + 2 * 65536;
  _Float16* W2nf = Wb5 + 3 * 65536;
  _Float16* PW2f = Wb5 + 4 * 65536;

  // 1. all preprocessing (W4f K=128: one-hot half removed)
  prepk<<<1696, 64, 0, stream>>>(g1, g2, eew1, prw1, eeb1, prb1, eeb2,
                                 eew2, new1, new2, prw2,
                                 Xext, W4f, Wb5, bias4);
  // 2. AB: z0 = big4 panel (K=128 + one-hot epilogue; Qm slice -> QmT
  //    transposed), z1 = H1
  gemm2<2, 2><<<dim3(16, 16, 2), 256, 0, stream>>>(
      Xext, Xext, 128, 128, 1.f, 1.f,
      W4f, W1nf, 128, 32, 4, 4, bias4, neb1,
      eew1, nullptr, QmT,
      (void*)XW16, (void*)H1, 2048, 512, 1, 0, 0, 1, 4);
  // 3. heavy fused per-edge pipeline -> S
  heavy_mfma<<<dim3(NN, 1, 2), 512, 0, stream>>>(XW16, W2f, WEf, QmT, Sv);
  // 4. CD: z0 = emb, z1 = intra (MT=1: 16 rows/block)
  gemm2<2, 1><<<dim3(32, 1, 2), 256, 0, stream>>>(
      H1, Sv, 512, 512, 1.f, 1.f / 256.f,
      W2nf, PW2f, 8, 8, 16, 16, neb2, prb2,
      nullptr, nullptr, nullptr,
      (void*)emb, (void*)intra, 128, 128, 0, 0, 0, 0, 1);
  // 5. interact + l2norms + update + logit dots (512 thr, 4-way chunked)
  interupd<<<dim3(NN, 2), 512, 0, stream>>>(emb, intra, upw, upb, agw, updv, lgv);
  // 6. softmax-aggregate + cosine
  aggfin<<<1, 1024, 0, stream>>>(updv, lgv, out);
}

// Round 17
// 107.611 us; speedup vs baseline: 1.0598x; 1.0598x over previous
//
#include <hip/hip_runtime.h>
#include <math.h>

#define NN 256
#define DD 128
#define HH 512

// ---------------- workspace layout (float offsets) ----------------
#define WS_XW    0         // fp16 [2][256][2048] panel Ae|Ce|Pp|Qm   (524288 f)
#define WS_XEXT  524288    // [512][128] f32 (65536 f); dead after AB:
#define WS_EMB   524288    //   emb [2][256][128] (65536 f)
#define WS_INTRA 589824    //   intra [2][256][128] (65536 f)
#define WS_W4F   720896    // fp16 512 frags x 512 halves (131072 f); dead after AB:
#define WS_UPD   720896    //   upd [2][256][128] (65536 f)
#define WS_H1    1114112   // [512][512] f32 (262144 f)
#define WS_S     1376256   // [2][256][512] f32 (262144 f)
#define WS_WB5   1638400   // fp16 5 x 128 frags (163840 f)
#define WS_B4    1802240   // bias4 [2048] f32
#define WS_LGV   1804288   // lgv [2][256] f32
// total 1804800 floats = 6.88 MB

typedef __attribute__((ext_vector_type(8))) _Float16 half8;
typedef __attribute__((ext_vector_type(4))) _Float16 half4v;
typedef __attribute__((ext_vector_type(4))) float f32x4;

__device__ __forceinline__ void gload_lds16(const _Float16* g, _Float16* l) {
  __builtin_amdgcn_global_load_lds(
      (const __attribute__((address_space(1))) unsigned*)g,
      (__attribute__((address_space(3))) unsigned*)l, 16, 0, 0);
}

#define WAITV(N) asm volatile("s_waitcnt vmcnt(" #N ")" ::: "memory")
#define RBARRIER() do { __builtin_amdgcn_s_barrier(); \
                        asm volatile("" ::: "memory"); } while (0)

// ================= prep kernel: all swizzles + Xext + bias4 =================
__global__ void prepk(const float* __restrict__ g1, const float* __restrict__ g2,
                      const float* __restrict__ eew1, const float* __restrict__ prw1,
                      const float* __restrict__ eeb1, const float* __restrict__ prb1,
                      const float* __restrict__ eeb2, const float* __restrict__ eew2,
                      const float* __restrict__ new1, const float* __restrict__ new2,
                      const float* __restrict__ prw2,
                      float* __restrict__ Xext, _Float16* __restrict__ W4f,
                      _Float16* __restrict__ Wb5, float* __restrict__ bias4)
{
  const int b = blockIdx.x, l = threadIdx.x;
  const int low = l & 15, q = l >> 4;
  if (b < 512) {                // big-4 weight frags (K=128, N=2048)
    const int f = b;
    const int kcI = f >> 7, ntI = f & 127;
    const int n = ntI * 16 + low, slice = n >> 9, np = n & 511;
    const int kb = kcI * 32 + q * 8;     // k in [0,128)
    half8 v;
    #pragma unroll
    for (int t = 0; t < 8; ++t) {
      const int k = kb + t;
      float val;
      if (slice == 0)      val = eew1[k * HH + np];
      else if (slice == 1) val = eew1[(384 + k) * HH + np];
      else if (slice == 2) val = prw1[k * HH + np];
      else                 val = prw1[(128 + k) * HH + np];
      v[t] = (_Float16)val;
    }
    *(half8*)&W4f[((size_t)f * 64 + l) * 8] = v;
  } else if (b < 1152) {        // five 128-frag weights
    const int idx = b - 512;
    const int which = idx >> 7, f = idx & 127;
    const float* src; int ld, nt;
    switch (which) {
      case 0:  src = eew2;            ld = 128; nt = 8;  break;   // W2f
      case 1:  src = prw1 + 256 * HH; ld = 512; nt = 32; break;   // WEf
      case 2:  src = new1;            ld = 512; nt = 32; break;   // W1nf
      case 3:  src = new2;            ld = 128; nt = 8;  break;   // W2nf
      default: src = prw2;            ld = 128; nt = 8;  break;   // PW2f
    }
    _Float16* dst = Wb5 + (size_t)which * 65536;
    const int kcI = f / nt, ntI = f % nt;
    const int n = ntI * 16 + low;
    const int kb = kcI * 32 + q * 8;
    half8 v;
    #pragma unroll
    for (int t = 0; t < 8; ++t) v[t] = (_Float16)src[(kb + t) * ld + n];
    *(half8*)&dst[((size_t)f * 64 + l) * 8] = v;
  } else if (b < 1664) {        // Xext rows = [g1; g2], 128 cols
    const int m = b - 1152;
    const int g = m >> 8, i = m & 255;
    const float* src = (g ? g2 : g1) + i * DD;
    float* dst = Xext + (size_t)m * DD;
    dst[l] = src[l];
    dst[64 + l] = src[64 + l];
  } else {                      // bias4
    const int n = (b - 1664) * 64 + l;
    float v = 0.f;
    if (n < 512) v = eeb1[n];
    else if (n >= 1024 && n < 1536) {
      const int h = n - 1024;
      float s = prb1[h];
      #pragma unroll 8
      for (int d = 0; d < 128; ++d) s = fmaf(eeb2[d], prw1[(256 + d) * HH + h], s);
      v = s;
    }
    bias4[n] = v;
  }
}

// ================= dual-config transposed MFMA GEMM =================
// oh: one-hot lookup add (f32 rows of eew1), z0 only.
template<int FT, int MT>
__global__ __launch_bounds__(256, 2)
void gemm2(const float* B0, const float* B1, int ldb0, int ldb1,
           float sc0, float sc1,
           const _Float16* A0, const _Float16* A1, int nt0, int nt1,
           int kcn0, int kcn1, const float* bias0, const float* bias1,
           const float* oh0, const float* oh1,
           void* O0, void* O1, int ldo0, int ldo1,
           int half0, int half1, int relu0, int relu1, int ylim1)
{
  const int z = blockIdx.z;
  if (z == 1 && (int)blockIdx.y >= ylim1) return;
  const float* Bsrc = z ? B1 : B0;
  const _Float16* Af = z ? A1 : A0;
  const float* bias = z ? bias1 : bias0;
  const float* ohp = z ? oh1 : oh0;
  void* Out = z ? O1 : O0;
  const int ldb = z ? ldb1 : ldb0, ntTot = z ? nt1 : nt0;
  const int kcN = z ? kcn1 : kcn0, ldo = z ? ldo1 : ldo0;
  const int ohalf = z ? half1 : half0, orelu = z ? relu1 : relu0;
  const float sc = z ? sc1 : sc0;

  const int tid = threadIdx.x;
  const int w = tid >> 6, l = tid & 63, low = l & 15, q = l >> 4;
  const int mb = blockIdx.x * (MT * 16);
  const int nb = (blockIdx.y * 4 + w) * (FT * 16);
  f32x4 acc[FT][MT];
  #pragma unroll
  for (int ft = 0; ft < FT; ++ft)
    #pragma unroll
    for (int et = 0; et < MT; ++et) acc[ft][et] = (f32x4){0.f, 0.f, 0.f, 0.f};

  for (int kc = 0; kc < kcN; ++kc) {
    const int k0 = kc * 32 + q * 8;
    half8 bfr[MT];
    #pragma unroll
    for (int et = 0; et < MT; ++et) {
      const float* p = Bsrc + (size_t)(mb + et * 16 + low) * ldb + k0;
      const float4 b0 = *(const float4*)p;
      const float4 b1 = *(const float4*)(p + 4);
      half8 v;
      v[0] = (_Float16)(b0.x * sc); v[1] = (_Float16)(b0.y * sc);
      v[2] = (_Float16)(b0.z * sc); v[3] = (_Float16)(b0.w * sc);
      v[4] = (_Float16)(b1.x * sc); v[5] = (_Float16)(b1.y * sc);
      v[6] = (_Float16)(b1.z * sc); v[7] = (_Float16)(b1.w * sc);
      bfr[et] = v;
    }
    #pragma unroll
    for (int ft = 0; ft < FT; ++ft) {
      const int ng = (nb >> 4) + ft;
      const half8 af = *(const half8*)&Af[((size_t)(kc * ntTot + ng) * 64 + l) * 8];
      #pragma unroll
      for (int et = 0; et < MT; ++et)
        acc[ft][et] = __builtin_amdgcn_mfma_f32_16x16x32_f16(af, bfr[et], acc[ft][et], 0, 0, 0);
    }
  }
  #pragma unroll
  for (int ft = 0; ft < FT; ++ft) {
    const int n0 = nb + ft * 16 + q * 4;
    const float4 bs = *(const float4*)&bias[n0];
    #pragma unroll
    for (int et = 0; et < MT; ++et) {
      const int m = mb + et * 16 + low;
      float vx = acc[ft][et][0] + bs.x;
      float vy = acc[ft][et][1] + bs.y;
      float vz = acc[ft][et][2] + bs.z;
      float vw = acc[ft][et][3] + bs.w;
      if (ohp) {
        const int i = m & 255;
        if (n0 < 512) {
          const float4 ov = *(const float4*)&ohp[(size_t)(128 + i) * 512 + n0];
          vx += ov.x; vy += ov.y; vz += ov.z; vw += ov.w;
        } else if (n0 < 1024) {
          const float4 ov = *(const float4*)&ohp[(size_t)(512 + i) * 512 + (n0 - 512)];
          vx += ov.x; vy += ov.y; vz += ov.z; vw += ov.w;
        }
      }
      if (orelu) {
        vx = fmaxf(vx, 0.f); vy = fmaxf(vy, 0.f);
        vz = fmaxf(vz, 0.f); vw = fmaxf(vw, 0.f);
      }
      if (ohalf) {
        half4v pk;
        pk[0] = (_Float16)vx; pk[1] = (_Float16)vy;
        pk[2] = (_Float16)vz; pk[3] = (_Float16)vw;
        *(half4v*)((_Float16*)Out + (size_t)m * ldo + n0) = pk;
      } else {
        *(float4*)((float*)Out + (size_t)m * ldo + n0) = make_float4(vx, vy, vz, vw);
      }
    }
  }
}

// ================= fused heavy edge kernel (R13/R15 version — proven 68us) ==
// grid (256 i, 1, 2 g), 512 threads / 8 waves; 256 j in two 128-j halves.
// 3-buffer ring + counted vmcnt + raw barrier; float4 Sp RMW; MFMA e-reduce.
// R14 (32-e waves, 1 blk/CU) and R16 (QmT transposed loads) both REGRESSED —
// this structure is the verified local optimum.
__global__ __launch_bounds__(512, 4)
void heavy_mfma(const _Float16* __restrict__ XW, const _Float16* __restrict__ W2fg,
                const _Float16* __restrict__ WEf, float* __restrict__ SG)
{
  __shared__ _Float16 Ut[128 * DD];      // 32 KB, XOR-swizzled 8B blocks
  __shared__ _Float16 Sb[3][4096];       // 24 KB staging ring (W2f/WEf)
  __shared__ _Float16 AeH[HH];           // 1 KB
  __shared__ float PpL[HH];              // 2 KB
  __shared__ float Sp[8][HH];            // 16 KB per-wave S partials
  const int g = blockIdx.z, i = blockIdx.x;
  const int tid = threadIdx.x;
  const _Float16* Xg = XW + (size_t)g * NN * 2048;
  const _Float16* rowI = Xg + (size_t)i * 2048;
  const int w = tid >> 6, l = tid & 63, low = l & 15, q = l >> 4;
  const int xsw = (low & 7) << 1;
  const half8 hz = (half8)((_Float16)0);

  AeH[tid] = rowI[tid];
  PpL[tid] = (float)rowI[1024 + tid];
  #pragma unroll
  for (int t = 0; t < 8; ++t) ((float*)Sp)[tid + t * 512] = 0.f;

  for (int h2 = 0; h2 < 2; ++h2) {
    const int jb = h2 * 128;
    const int j = jb + w * 16 + low;     // this lane's j-row (16 per wave)
    const int e = w * 16 + low;          // local Ut row

    // ---------- stage 1: Ut[e][c] for this wave's 16 e ----------
    __syncthreads();                     // Sb WAR across halves/stages
    gload_lds16(W2fg + (size_t)w * 512 + l * 8, &Sb[0][w * 512]);
    gload_lds16(W2fg + 4096 + (size_t)w * 512 + l * 8, &Sb[1][w * 512]);
    {
      half8 ce_cur = *(const half8*)&Xg[(size_t)j * 2048 + 512 + q * 8];
      f32x4 acc[8];
      #pragma unroll
      for (int ct = 0; ct < 8; ++ct) acc[ct] = (f32x4){0.f, 0.f, 0.f, 0.f};
      for (int kc = 0; kc < 16; ++kc) {
        half8 ce_nxt = hz;
        if (kc < 15)
          ce_nxt = *(const half8*)&Xg[(size_t)j * 2048 + 512 + (kc + 1) * 32 + q * 8];
        if (kc == 0)       WAITV(1);
        else if (kc == 15) WAITV(0);
        else               WAITV(2);
        RBARRIER();
        if (kc < 14)
          gload_lds16(W2fg + (size_t)(kc + 2) * 4096 + w * 512 + l * 8,
                      &Sb[(kc + 2) % 3][w * 512]);
        const half8 a = *(const half8*)&AeH[kc * 32 + q * 8];
        const half8 bfr = __builtin_elementwise_max(a + ce_cur, hz);
        const _Float16* sb = &Sb[kc % 3][0];
        __builtin_amdgcn_s_setprio(1);
        #pragma unroll
        for (int ct = 0; ct < 8; ++ct) {
          const half8 wf = *(const half8*)&sb[ct * 512 + l * 8];
          acc[ct] = __builtin_amdgcn_mfma_f32_16x16x32_f16(wf, bfr, acc[ct], 0, 0, 0);
        }
        __builtin_amdgcn_s_setprio(0);
        ce_cur = ce_nxt;
      }
      // write Ut (wave-private rows)
      #pragma unroll
      for (int ct = 0; ct < 8; ++ct) {
        const int cb2 = ct * 4 + q;
        half4v pk;
        pk[0] = (_Float16)acc[ct][0]; pk[1] = (_Float16)acc[ct][1];
        pk[2] = (_Float16)acc[ct][2]; pk[3] = (_Float16)acc[ct][3];
        *(half4v*)&Ut[e * DD + ((cb2 ^ xsw) << 2)] = pk;
      }
    }

    // ---------- stage 2: WEf via ring; D2[m=e][n=h]; e-reduce via MFMA ----------
    __syncthreads();                     // Sb WAR: stage1 compute(15) read S0
    gload_lds16(WEf + (size_t)((w >> 1) * 32 + 0 + (w & 1)) * 512 + l * 8,
                &Sb[0][w * 512]);
    gload_lds16(WEf + (size_t)((w >> 1) * 32 + 2 + (w & 1)) * 512 + l * 8,
                &Sb[1][w * 512]);
    {
      half8 bfr2[4];
      #pragma unroll
      for (int kc2 = 0; kc2 < 4; ++kc2) {
        const int cb0 = kc2 * 8 + q * 2;
        bfr2[kc2] = *(const half8*)&Ut[e * DD + ((cb0 ^ xsw) << 2)];
      }
      const half4v onesv = {(_Float16)1.f, (_Float16)1.f, (_Float16)1.f, (_Float16)1.f};
      for (int cc = 0; cc < 16; ++cc) {
        if (cc == 15) WAITV(0);
        else          WAITV(1);
        RBARRIER();
        const _Float16* sb = &Sb[cc % 3][0];
        #pragma unroll
        for (int t = 0; t < 2; ++t) {
          const int hc = cc * 2 + t;
          const int h0 = hc * 16;
          f32x4 acc2 = (f32x4){0.f, 0.f, 0.f, 0.f};
          __builtin_amdgcn_s_setprio(1);
          #pragma unroll
          for (int kc2 = 0; kc2 < 4; ++kc2) {
            const half8 af = *(const half8*)&sb[(kc2 * 2 + t) * 512 + l * 8];
            acc2 = __builtin_amdgcn_mfma_f32_16x16x32_f16(bfr2[kc2], af, acc2, 0, 0, 0);
          }
          __builtin_amdgcn_s_setprio(0);
          const float pp = PpL[h0 + low];
          half4v rv;
          #pragma unroll
          for (int r = 0; r < 4; ++r) {
            const int jr = jb + w * 16 + q * 4 + r;
            const float qv = (float)Xg[(size_t)jr * 2048 + 1536 + h0 + low];
            rv[r] = (_Float16)fmaxf(pp + qv + acc2[r], 0.f);
          }
          f32x4 red = __builtin_amdgcn_mfma_f32_16x16x16f16(
              rv, onesv, (f32x4){0.f, 0.f, 0.f, 0.f}, 0, 0, 0);
          if (low == 0) {
            float4* sp = (float4*)&Sp[w][h0 + q * 4];
            float4 v = *sp;
            v.x += red[0]; v.y += red[1]; v.z += red[2]; v.w += red[3];
            *sp = v;
          }
        }
        if (cc < 14)
          gload_lds16(WEf + (size_t)((w >> 1) * 32 + 2 * (cc + 2) + (w & 1)) * 512 + l * 8,
                      &Sb[(cc + 2) % 3][w * 512]);
      }
    }
  }
  __syncthreads();
  float s = 0.f;
  #pragma unroll
  for (int w2 = 0; w2 < 8; ++w2) s += Sp[w2][tid];
  SG[((size_t)g * NN + i) * HH + tid] = s;
}

// ====== fused interact + l2norm + update + logit row-dot; 512 threads ======
__global__ void interupd(const float* __restrict__ embG, const float* __restrict__ intraG,
                         const float* __restrict__ upw, const float* __restrict__ upb,
                         const float* __restrict__ agw,
                         float* __restrict__ updG, float* __restrict__ lgv)
{
  const int i = blockIdx.x, dir = blockIdx.y;
  const int tid = threadIdx.x, d = tid & 127, jc = tid >> 7;
  __shared__ float pN[4][DD], pS[4][DD], pdot[4][DD];
  __shared__ float vsm[3 * DD];
  __shared__ float pw[2][4];
  __shared__ float pw2[2];
  const float* A = embG + dir * NN * DD;
  const float* Bp = embG + (1 - dir) * NN * DD;
  const float av = A[i * DD + d];
  {
    float accN = 0.f, accS = 0.f;
    #pragma unroll 4
    for (int j = jc * 64; j < jc * 64 + 64; ++j) {
      const float bv = Bp[j * DD + d];
      accN = fmaf(bv, __expf(av * bv), accN);
      accS += bv;
    }
    pN[jc][d] = accN; pS[jc][d] = accS;
  }
  __syncthreads();
  float cv = 0.f, iv = 0.f;
  if (jc == 0) {
    const float accN = pN[0][d] + pN[1][d] + pN[2][d] + pN[3][d];
    const float accS = pS[0][d] + pS[1][d] + pS[2][d] + pS[3][d];
    cv = accN / (256.f * av * accS);
    iv = intraG[dir * NN * DD + i * DD + d];
    float q0 = av * av, q1 = iv * iv, q2 = cv * cv;
    #pragma unroll
    for (int st = 1; st < 64; st <<= 1) {
      q0 += __shfl_xor(q0, st);
      q1 += __shfl_xor(q1, st);
      q2 += __shfl_xor(q2, st);
    }
    const int w = d >> 6;
    if ((d & 63) == 0) { pw[w][0] = q0; pw[w][1] = q1; pw[w][2] = q2; }
  }
  __syncthreads();
  if (jc == 0) {
    const float n0 = 1.f / fmaxf(sqrtf(pw[0][0] + pw[1][0]), 1e-12f);
    const float n1 = 1.f / fmaxf(sqrtf(pw[0][1] + pw[1][1]), 1e-12f);
    const float n2 = 1.f / fmaxf(sqrtf(pw[0][2] + pw[1][2]), 1e-12f);
    vsm[d] = av * n0; vsm[DD + d] = iv * n1; vsm[2 * DD + d] = cv * n2;
  }
  __syncthreads();
  {
    float pd = (jc == 0) ? upb[d] : 0.f;
    #pragma unroll 8
    for (int k = jc * 96; k < jc * 96 + 96; ++k)
      pd = fmaf(vsm[k], upw[k * DD + d], pd);
    pdot[jc][d] = pd;
  }
  __syncthreads();
  if (jc == 0) {
    const float acc = pdot[0][d] + pdot[1][d] + pdot[2][d] + pdot[3][d];
    updG[dir * NN * DD + i * DD + d] = acc;
    float lp = acc * agw[d];
    #pragma unroll
    for (int st = 1; st < 64; st <<= 1) lp += __shfl_xor(lp, st);
    if ((d & 63) == 0) pw2[d >> 6] = lp;
  }
  __syncthreads();
  if (tid == 0) lgv[dir * NN + i] = pw2[0] + pw2[1];
}

// ==== aggregate: softmax(lgv) + weighted sum + cosine; 1024 threads ====
__global__ void aggfin(const float* __restrict__ updG, const float* __restrict__ lgv,
                       float* __restrict__ out)
{
  __shared__ float mp[2][4][DD];
  __shared__ float sg[2][NN];
  __shared__ float redd[1024];
  const int t = threadIdx.x;
  const int g = t >> 9, tl = t & 511, jc = tl >> 7, d = tl & 127;
  const float* U = updG + g * NN * DD;
  const float lg = (tl < NN) ? lgv[g * NN + tl] : -1e30f;
  redd[t] = lg;
  __syncthreads();
  for (int st = 256; st > 0; st >>= 1) {
    if (tl < st) redd[t] = fmaxf(redd[t], redd[t + st]);
    __syncthreads();
  }
  const float mx = redd[g << 9];
  __syncthreads();
  const float e = (tl < NN) ? __expf(lg - mx) : 0.f;
  redd[t] = e;
  __syncthreads();
  for (int st = 256; st > 0; st >>= 1) {
    if (tl < st) redd[t] += redd[t + st];
    __syncthreads();
  }
  if (tl < NN) sg[g][tl] = e / redd[g << 9];
  __syncthreads();
  {
    float rp = 0.f;
    #pragma unroll 4
    for (int jj = jc * 64; jj < jc * 64 + 64; ++jj)
      rp = fmaf(sg[g][jj], U[jj * DD + d], rp);
    mp[g][jc][d] = rp;
  }
  __syncthreads();
  if (t < DD) {
    const float r0 = mp[0][0][t] + mp[0][1][t] + mp[0][2][t] + mp[0][3][t];
    const float r1 = mp[1][0][t] + mp[1][1][t] + mp[1][2][t] + mp[1][3][t];
    redd[t] = r0 * r1; redd[128 + t] = r0 * r0; redd[256 + t] = r1 * r1;
  }
  __syncthreads();
  for (int st = 64; st > 0; st >>= 1) {
    if (t < st) redd[t] += redd[t + st];
    else if (t >= 128 && t < 128 + st) redd[t] += redd[t + st];
    else if (t >= 256 && t < 256 + st) redd[t] += redd[t + st];
    __syncthreads();
  }
  if (t == 0)
    out[0] = (redd[0] / fmaxf(sqrtf(redd[128]) * sqrtf(redd[256]), 1e-8f) + 1.f) * 0.5f;
}

extern "C" void kernel_launch(void* const* d_in, const int* in_sizes, int n_in,
                              void* d_out, int out_size, void* d_ws, size_t ws_size,
                              hipStream_t stream)
{
  (void)in_sizes; (void)n_in; (void)out_size; (void)ws_size;
  const float* g1   = (const float*)d_in[0];
  const float* g2   = (const float*)d_in[1];
  const float* new1 = (const float*)d_in[2];
  const float* neb1 = (const float*)d_in[3];
  const float* new2 = (const float*)d_in[4];
  const float* neb2 = (const float*)d_in[5];
  const float* eew1 = (const float*)d_in[6];
  const float* eeb1 = (const float*)d_in[7];
  const float* eew2 = (const float*)d_in[8];
  const float* eeb2 = (const float*)d_in[9];
  const float* prw1 = (const float*)d_in[10];
  const float* prb1 = (const float*)d_in[11];
  const float* prw2 = (const float*)d_in[12];
  const float* prb2 = (const float*)d_in[13];
  const float* upw  = (const float*)d_in[14];
  const float* upb  = (const float*)d_in[15];
  const float* agw  = (const float*)d_in[16];
  const float* agb  = (const float*)d_in[17];
  (void)agb; // constant logit shift cancels in softmax
  float* W = (float*)d_ws;
  float* out = (float*)d_out;

  _Float16* XW16 = (_Float16*)(W + WS_XW);
  float* Xext    = W + WS_XEXT;
  float* emb     = W + WS_EMB;
  float* intra   = W + WS_INTRA;
  _Float16* W4f  = (_Float16*)(W + WS_W4F);
  float* updv    = W + WS_UPD;
  float* H1      = W + WS_H1;
  float* Sv      = W + WS_S;
  _Float16* Wb5  = (_Float16*)(W + WS_WB5);
  float* bias4   = W + WS_B4;
  float* lgv     = W + WS_LGV;
  _Float16* W2f  = Wb5;
  _Float16* WEf  = Wb5 + 65536;
  _Float16* W1nf = Wb5 + 2 * 65536;
  _Float16* W2nf = Wb5 + 3 * 65536;
  _Float16* PW2f = Wb5 + 4 * 65536;

  // 1. all preprocessing (W4f K=128: one-hot half removed)
  prepk<<<1696, 64, 0, stream>>>(g1, g2, eew1, prw1, eeb1, prb1, eeb2,
                                 eew2, new1, new2, prw2,
                                 Xext, W4f, Wb5, bias4);
  // 2. AB: z0 = big4 panel (K=128 + one-hot lookup epilogue), z1 = H1
  gemm2<2, 2><<<dim3(16, 16, 2), 256, 0, stream>>>(
      Xext, Xext, 128, 128, 1.f, 1.f,
      W4f, W1nf, 128, 32, 4, 4, bias4, neb1,
      eew1, nullptr,
      (void*)XW16, (void*)H1, 2048, 512, 1, 0, 0, 1, 4);
  // 3. heavy fused per-edge pipeline -> S
  heavy_mfma<<<dim3(NN, 1, 2), 512, 0, stream>>>(XW16, W2f, WEf, Sv);
  // 4. CD: z0 = emb, z1 = intra (FT=1, 128 blocks — more CU coverage)
  gemm2<1, 1><<<dim3(32, 2, 2), 256, 0, stream>>>(
      H1, Sv, 512, 512, 1.f, 1.f / 256.f,
      W2nf, PW2f, 8, 8, 16, 16, neb2, prb2,
      nullptr, nullptr,
      (void*)emb, (void*)intra, 128, 128, 0, 0, 0, 0, 2);
  // 5. interact + l2norms + update + logit dots (512 thr, 4-way chunked)
  interupd<<<dim3(NN, 2), 512, 0, stream>>>(emb, intra, upw, upb, agw, updv, lgv);
  // 6. softmax-aggregate + cosine
  aggfin<<<1, 1024, 0, stream>>>(updv, lgv, out);
}